// Round 1
// baseline (11039.712 us; speedup 1.0000x reference)
//
#include <hip/hip_runtime.h>
#include <math.h>

#define BATCH 64
#define HDIM 1024
#define EDIM 1024
#define VOCAB 32000
#define TSTEPS 50
#define G4 4096      // 4*H
#define KCAT 2048    // EDIM + HDIM
#define STARTIDX 1

// ---------------------------------------------------------------------------
// init: xcat[b] = [ embedding[START_INDEX] | hidden[b] ],  c = 0
// ---------------------------------------------------------------------------
__global__ __launch_bounds__(256) void init_kernel(
    const float* __restrict__ hidden, const float* __restrict__ embedding,
    float* __restrict__ xcat, float* __restrict__ c)
{
    int tid = blockIdx.x * 256 + threadIdx.x;   // 0 .. 64*2048-1
    int b = tid >> 11;
    int j = tid & 2047;
    if (j < EDIM) {
        xcat[(size_t)b * KCAT + j] = embedding[(size_t)STARTIDX * EDIM + j];
    } else {
        int k = j - EDIM;
        xcat[(size_t)b * KCAT + j] = hidden[(size_t)b * HDIM + k];
        c[(size_t)b * HDIM + k] = 0.0f;
    }
}

// ---------------------------------------------------------------------------
// C_slice[s] (64 x N) = X[:, kbase:kbase+Ks] @ Wsel^T  (+ bias if non-null)
// Tile: 64 rows x 128 cols, 256 threads, 4x8 per-thread micro-tile, KC=16.
// W is [W0 | W1] concatenated along k with boundary at ldw (for gates);
// for a single weight pass W1 is unused (kbase < ldw always).
// Deterministic: no atomics; K-slices write separate partial buffers.
// ---------------------------------------------------------------------------
__global__ __launch_bounds__(256) void gemm_xwt(
    const float* __restrict__ X, int ldx,
    const float* __restrict__ W0, const float* __restrict__ W1, int ldw,
    const float* __restrict__ bias,
    float* __restrict__ C, size_t c_slice_stride,
    int N, int Ktotal, int nslices, int coltiles)
{
    __shared__ float Xs[16][68];    // [kk][row], pad to keep b128 alignment
    __shared__ float Ws[16][136];   // [kk][col]

    const int tid = threadIdx.x;
    const int bx  = blockIdx.x;
    const int s   = bx / coltiles;
    const int ct  = bx - s * coltiles;
    const int Ks  = Ktotal / nslices;
    const int kbase = s * Ks;
    const float* Xp = X + kbase;
    const float* Wp = (kbase < ldw) ? (W0 + kbase) : (W1 + (kbase - ldw));
    const int colBase = ct * 128;

    const int row0 = (tid >> 4) * 4;      // 0..60
    const int col0 = (tid & 15) * 8;      // 0..120
    const int lr4  = tid >> 2;            // 0..63
    const int lk4  = (tid & 3) << 2;      // 0,4,8,12

    float acc[4][8];
#pragma unroll
    for (int i = 0; i < 4; ++i)
#pragma unroll
        for (int j = 0; j < 8; ++j) acc[i][j] = 0.0f;

    const float* xg = Xp + (size_t)lr4 * ldx + lk4;
    const float* wg0 = Wp + (size_t)(colBase + lr4) * ldw + lk4;
    const float* wg1 = Wp + (size_t)(colBase + 64 + lr4) * ldw + lk4;

    for (int k0 = 0; k0 < Ks; k0 += 16) {
        float4 xv = *(const float4*)(xg + k0);
        float4 w0 = *(const float4*)(wg0 + k0);
        float4 w1 = *(const float4*)(wg1 + k0);
        __syncthreads();   // prior iteration's LDS reads done
        Xs[lk4+0][lr4] = xv.x; Xs[lk4+1][lr4] = xv.y;
        Xs[lk4+2][lr4] = xv.z; Xs[lk4+3][lr4] = xv.w;
        Ws[lk4+0][lr4] = w0.x; Ws[lk4+1][lr4] = w0.y;
        Ws[lk4+2][lr4] = w0.z; Ws[lk4+3][lr4] = w0.w;
        Ws[lk4+0][64+lr4] = w1.x; Ws[lk4+1][64+lr4] = w1.y;
        Ws[lk4+2][64+lr4] = w1.z; Ws[lk4+3][64+lr4] = w1.w;
        __syncthreads();
#pragma unroll
        for (int kk = 0; kk < 16; ++kk) {
            float4 av = *(const float4*)&Xs[kk][row0];
            float4 b0 = *(const float4*)&Ws[kk][col0];
            float4 b1 = *(const float4*)&Ws[kk][col0 + 4];
            float a[4] = {av.x, av.y, av.z, av.w};
            float bb[8] = {b0.x, b0.y, b0.z, b0.w, b1.x, b1.y, b1.z, b1.w};
#pragma unroll
            for (int i = 0; i < 4; ++i)
#pragma unroll
                for (int j = 0; j < 8; ++j)
                    acc[i][j] += a[i] * bb[j];
        }
    }

    float* Cs = C + (size_t)s * c_slice_stride;
#pragma unroll
    for (int i = 0; i < 4; ++i) {
        const int r = row0 + i;
        float* crow = Cs + (size_t)r * N + colBase + col0;
#pragma unroll
        for (int j = 0; j < 8; ++j) {
            float v = acc[i][j];
            if (bias) v += bias[colBase + col0 + j];
            crow[j] = v;
        }
    }
}

// ---------------------------------------------------------------------------
// cell: gate[b][j] = sum_s gpart[s][b][j] + b_ih[j] + b_hh[j]  (fixed order ->
// deterministic), then LSTM update; h_new written into xcat[:,EDIM:].
// ---------------------------------------------------------------------------
__global__ __launch_bounds__(256) void cell_kernel(
    const float* __restrict__ gpart,   // [8][64*4096]
    const float* __restrict__ b_ih, const float* __restrict__ b_hh,
    float* __restrict__ c, float* __restrict__ xcat)
{
    int tid = blockIdx.x * 256 + threadIdx.x;   // 0..65535
    int b = tid >> 10;
    int k = tid & 1023;
    size_t base = (size_t)b * G4;
    float g[4];
#pragma unroll
    for (int q = 0; q < 4; ++q) {
        int j = k + q * HDIM;
        float v = b_ih[j] + b_hh[j];
#pragma unroll
        for (int sN = 0; sN < 8; ++sN)
            v += gpart[(size_t)sN * ((size_t)BATCH * G4) + base + j];
        g[q] = v;
    }
    float sig_i = 1.0f / (1.0f + expf(-g[0]));
    float sig_f = 1.0f / (1.0f + expf(-g[1]));
    float sig_o = 1.0f / (1.0f + expf(-g[3]));
    float cn = sig_f * c[tid] + sig_i * tanhf(g[2]);
    float hn = sig_o * tanhf(cn);
    c[tid] = cn;
    xcat[(size_t)b * KCAT + EDIM + k] = hn;
}

// ---------------------------------------------------------------------------
// softmax + argmax (first-index tie-break, matches np.argmax) + prob write +
// pred write (as float; out buffer is read as fp32) + gather next embedding.
// One block per batch row.
// ---------------------------------------------------------------------------
__global__ __launch_bounds__(256) void softmax_kernel(
    const float* __restrict__ logits, const float* __restrict__ embedding,
    float* __restrict__ probs, float* __restrict__ preds,
    float* __restrict__ xcat, int t)
{
    const int b = blockIdx.x;
    const int tid = threadIdx.x;
    const float* row = logits + (size_t)b * VOCAB;
    __shared__ float sv[256];
    __shared__ int   si[256];

    // pass 1: max + first-index argmax
    float m = -INFINITY; int mi = 0;
    for (int v = tid; v < VOCAB; v += 256) {
        float x = row[v];
        if (x > m) { m = x; mi = v; }   // strict > keeps earliest in-thread
    }
    sv[tid] = m; si[tid] = mi;
    __syncthreads();
    for (int stp = 128; stp > 0; stp >>= 1) {
        if (tid < stp) {
            float vo = sv[tid + stp]; int io = si[tid + stp];
            if (vo > sv[tid] || (vo == sv[tid] && io < si[tid])) {
                sv[tid] = vo; si[tid] = io;
            }
        }
        __syncthreads();
    }
    const float gmax = sv[0];
    const int   gidx = si[0];
    __syncthreads();   // before reusing sv

    // pass 2: sum of exp (deterministic tree order)
    float sum = 0.0f;
    for (int v = tid; v < VOCAB; v += 256) sum += expf(row[v] - gmax);
    sv[tid] = sum;
    __syncthreads();
    for (int stp = 128; stp > 0; stp >>= 1) {
        if (tid < stp) sv[tid] += sv[tid + stp];
        __syncthreads();
    }
    const float inv = 1.0f / sv[0];

    // pass 3: write probabilities  (layout: probs[b][t][v])
    float* orow = probs + ((size_t)b * TSTEPS + t) * VOCAB;
    for (int v = tid; v < VOCAB; v += 256) orow[v] = expf(row[v] - gmax) * inv;

    if (tid == 0) preds[(size_t)b * TSTEPS + t] = (float)gidx;

    // gather next step's embedding row into xcat[:, 0:EDIM]
    const float* erow = embedding + (size_t)gidx * EDIM;
    float* xrow = xcat + (size_t)b * KCAT;
    for (int v = tid; v < EDIM; v += 256) xrow[v] = erow[v];
}

// ---------------------------------------------------------------------------
extern "C" void kernel_launch(void* const* d_in, const int* in_sizes, int n_in,
                              void* d_out, int out_size, void* d_ws, size_t ws_size,
                              hipStream_t stream)
{
    const float* hidden    = (const float*)d_in[0];
    const float* embedding = (const float*)d_in[1];
    const float* W_ih      = (const float*)d_in[2];
    const float* W_hh      = (const float*)d_in[3];
    const float* b_ih      = (const float*)d_in[4];
    const float* b_hh      = (const float*)d_in[5];
    const float* W_out     = (const float*)d_in[6];
    const float* b_out     = (const float*)d_in[7];

    float* probs = (float*)d_out;                               // B*T*V fp32
    float* preds = probs + (size_t)BATCH * TSTEPS * VOCAB;      // B*T as fp32

    // workspace layout (floats):
    float* ws     = (float*)d_ws;
    float* xcat   = ws;                                   // 64*2048
    float* cbuf   = xcat + (size_t)BATCH * KCAT;          // 64*1024
    float* gpart  = cbuf + (size_t)BATCH * HDIM;          // 8 * 64*4096
    float* logits = gpart + (size_t)8 * BATCH * G4;       // 64*32000
    // total ~4.34M floats = ~16.6 MB

    init_kernel<<<(BATCH * KCAT) / 256, 256, 0, stream>>>(hidden, embedding, xcat, cbuf);

    for (int t = 0; t < TSTEPS; ++t) {
        // gates: N=4096, K=2048 split into 8 slices (fills 256 CUs),
        // W = [W_ih | W_hh] along k with boundary at ldw=1024
        gemm_xwt<<<8 * 32, 256, 0, stream>>>(
            xcat, KCAT, W_ih, W_hh, HDIM,
            nullptr, gpart, (size_t)BATCH * G4,
            G4, KCAT, 8, 32);

        cell_kernel<<<(BATCH * HDIM) / 256, 256, 0, stream>>>(
            gpart, b_ih, b_hh, cbuf, xcat);

        // logits: X = h slice of xcat (ldx=2048), N=32000, K=1024
        gemm_xwt<<<VOCAB / 128, 256, 0, stream>>>(
            xcat + EDIM, KCAT, W_out, W_out, HDIM,
            b_out, logits, 0,
            VOCAB, HDIM, 1, VOCAB / 128);

        softmax_kernel<<<BATCH, 256, 0, stream>>>(
            logits, embedding, probs, preds, xcat, t);
    }
}